// Round 13
// baseline (305.419 us; speedup 1.0000x reference)
//
#include <hip/hip_runtime.h>
#include <math.h>

constexpr int NN = 20000;   // nodes
constexpr int NE = 320000;  // edges
constexpr int MROWS = 20224; // A1/A3 row padding
constexpr int MH = 20096;   // H1 rows (157 groups of 128)

typedef __bf16 bf16x8 __attribute__((ext_vector_type(8)));
typedef float f32x4 __attribute__((ext_vector_type(4)));

__device__ __forceinline__ unsigned short f2bf(float f) {
  unsigned int u = __float_as_uint(f);
  unsigned int r = (u + 0x7FFFu + ((u >> 16) & 1u)) >> 16;
  return (unsigned short)r;
}

// bijective XCD chunking (m204)
__device__ __forceinline__ int xcd_swizzle(int bid, int T) {
  int q = T >> 3, r = T & 7;
  int x = bid & 7, i = bid >> 3;
  return (x < r ? x * (q + 1) : r * (q + 1) + (x - r) * q) + i;
}

// ---------------- fast zero ----------------
__global__ __launch_bounds__(256) void zero_kernel(int4* __restrict__ p, int n4) {
  int i = blockIdx.x * 256 + threadIdx.x;
  if (i < n4) p[i] = make_int4(0, 0, 0, 0);
}

// ---------------- degree count ----------------
__global__ void deg_count_kernel(const int* __restrict__ src, const int* __restrict__ dst,
                                 int* __restrict__ degs, int* __restrict__ degd, int nE) {
  int e = blockIdx.x * blockDim.x + threadIdx.x;
  if (e < nE) {
    atomicAdd(degs + src[e], 1);
    atomicAdd(degd + dst[e], 1);
  }
}

// ---------------- fused: exclusive scan of degd -> rowptr, plus ns/nd norms --------
__global__ __launch_bounds__(1024) void scan_norm_kernel(
    const int* __restrict__ degs, const int* __restrict__ degd,
    int* __restrict__ rowptr, float* __restrict__ ns, float* __restrict__ nd, int n) {
  constexpr int T = 1024;
  const int ITEMS = (n + T - 1) / T;
  __shared__ int sums[T];
  int t = threadIdx.x;
  int base = t * ITEMS;
  int s = 0;
  for (int i = 0; i < ITEMS; ++i) {
    int idx = base + i;
    if (idx < n) {
      int dd = degd[idx];
      s += dd;
      ns[idx] = rsqrtf(fmaxf((float)degs[idx], 1.0f));
      nd[idx] = rsqrtf(fmaxf((float)dd, 1.0f));
    }
  }
  sums[t] = s;
  __syncthreads();
  for (int off = 1; off < T; off <<= 1) {
    int v = (t >= off) ? sums[t - off] : 0;
    __syncthreads();
    sums[t] += v;
    __syncthreads();
  }
  int ex = (t == 0) ? 0 : sums[t - 1];
  for (int i = 0; i < ITEMS; ++i) {
    int idx = base + i;
    if (idx < n) {
      rowptr[idx] = ex;
      ex += degd[idx];
    }
  }
  if (t == 0) rowptr[n] = sums[T - 1];
}

// ---------------- CSR fill ----------------
__global__ void csr_fill_kernel(const int* __restrict__ src, const int* __restrict__ dst,
                                const int* __restrict__ rowptr, int* __restrict__ cursor,
                                int* __restrict__ col, int nE) {
  int e = blockIdx.x * blockDim.x + threadIdx.x;
  if (e < nE) {
    int d = dst[e];
    int p = atomicAdd(cursor + d, 1);
    col[rowptr[d] + p] = src[e];
  }
}

// ---------------- fused weight convert: all 4 Wt[Npad][Kpad] in one launch ---------
// blockIdx.y row ranges: [0,832)=W1t, [832,960)=W2t, [960,1792)=W3t, [1792,2048)=W4t
__global__ __launch_bounds__(256) void wt_convert_all_kernel(
    const float* __restrict__ W1, const float* __restrict__ W2,
    const float* __restrict__ W3, const float* __restrict__ W4,
    unsigned short* __restrict__ W1t, unsigned short* __restrict__ W2t,
    unsigned short* __restrict__ W3t, unsigned short* __restrict__ W4t) {
  int n = blockIdx.y;
  int k = blockIdx.x * 256 + threadIdx.x;
  const float* W; unsigned short* Wt; int K, N, Kpad;
  if (n < 832)       { W = W1; Wt = W1t; K = 256; N = 800; Kpad = 256; }
  else if (n < 960)  { n -= 832;  W = W2; Wt = W2t; K = 800; N = 128; Kpad = 832; }
  else if (n < 1792) { n -= 960;  W = W3; Wt = W3t; K = 128; N = 800; Kpad = 128; }
  else               { n -= 1792; W = W4; Wt = W4t; K = 800; N = 256; Kpad = 832; }
  if (k >= Kpad) return;
  float v = (n < N && k < K) ? W[(size_t)k * N + n] : 0.f;
  Wt[(size_t)n * Kpad + k] = f2bf(v);
}

// ---------------- xb = bf16(x * ns[row]) pre-pass ----------------
__global__ __launch_bounds__(256) void scale_cvt_kernel(
    const float* __restrict__ x, const float* __restrict__ ns,
    unsigned short* __restrict__ xb) {
  int t = blockIdx.x * 256 + threadIdx.x;
  if (t >= NN * 32) return;
  int node = t >> 5;
  float sc = ns[node];
  float4 v1 = reinterpret_cast<const float4*>(x)[t * 2];
  float4 v2 = reinterpret_cast<const float4*>(x)[t * 2 + 1];
  uint4 o;
  o.x = f2bf(v1.x * sc) | ((unsigned)f2bf(v1.y * sc) << 16);
  o.y = f2bf(v1.z * sc) | ((unsigned)f2bf(v1.w * sc) << 16);
  o.z = f2bf(v2.x * sc) | ((unsigned)f2bf(v2.y * sc) << 16);
  o.w = f2bf(v2.z * sc) | ((unsigned)f2bf(v2.w * sc) << 16);
  reinterpret_cast<uint4*>(xb)[t] = o;
}

// ---------------- bf16 CSR gather (edge loop unrolled x2) ----------------
// EPI==0: bf16 sum -> out.
// EPI==1: v = sum*sDst+bias; bf16(v*snext[node]) -> out AND sigmoid(v) -> out2 (f32).
// EPI==2: v = sum*sDst+bias; sigmoid(v) -> out2 only.
template <int F, int EPI>
__global__ __launch_bounds__(256) void gatherb_kernel(
    const unsigned short* __restrict__ in, const int* __restrict__ rowptr,
    const int* __restrict__ col, const float* __restrict__ sDst,
    const float* __restrict__ bias, const float* __restrict__ snext,
    unsigned short* __restrict__ out, float* __restrict__ out2, int n) {
  constexpr int LPN = F / 8;
  constexpr int NPB = 256 / LPN;
  const int tid = threadIdx.x;
  const int node = blockIdx.x * NPB + tid / LPN;
  const int j = tid % LPN;
  if (node >= n) return;
  const int e0 = rowptr[node], e1 = rowptr[node + 1];
  float a[8] = {0.f, 0.f, 0.f, 0.f, 0.f, 0.f, 0.f, 0.f};
  int e = e0;
  for (; e + 1 < e1; e += 2) {  // 2 independent 16B loads in flight
    int c0 = col[e], c1 = col[e + 1];
    uint4 u0 = *reinterpret_cast<const uint4*>(in + (size_t)c0 * F + j * 8);
    uint4 u1 = *reinterpret_cast<const uint4*>(in + (size_t)c1 * F + j * 8);
    a[0] += __uint_as_float(u0.x << 16);
    a[1] += __uint_as_float(u0.x & 0xffff0000u);
    a[2] += __uint_as_float(u0.y << 16);
    a[3] += __uint_as_float(u0.y & 0xffff0000u);
    a[4] += __uint_as_float(u0.z << 16);
    a[5] += __uint_as_float(u0.z & 0xffff0000u);
    a[6] += __uint_as_float(u0.w << 16);
    a[7] += __uint_as_float(u0.w & 0xffff0000u);
    a[0] += __uint_as_float(u1.x << 16);
    a[1] += __uint_as_float(u1.x & 0xffff0000u);
    a[2] += __uint_as_float(u1.y << 16);
    a[3] += __uint_as_float(u1.y & 0xffff0000u);
    a[4] += __uint_as_float(u1.z << 16);
    a[5] += __uint_as_float(u1.z & 0xffff0000u);
    a[6] += __uint_as_float(u1.w << 16);
    a[7] += __uint_as_float(u1.w & 0xffff0000u);
  }
  if (e < e1) {
    int c = col[e];
    uint4 u = *reinterpret_cast<const uint4*>(in + (size_t)c * F + j * 8);
    a[0] += __uint_as_float(u.x << 16);
    a[1] += __uint_as_float(u.x & 0xffff0000u);
    a[2] += __uint_as_float(u.y << 16);
    a[3] += __uint_as_float(u.y & 0xffff0000u);
    a[4] += __uint_as_float(u.z << 16);
    a[5] += __uint_as_float(u.z & 0xffff0000u);
    a[6] += __uint_as_float(u.w << 16);
    a[7] += __uint_as_float(u.w & 0xffff0000u);
  }
  if (EPI == 0) {
    uint4 o;
    o.x = f2bf(a[0]) | ((unsigned)f2bf(a[1]) << 16);
    o.y = f2bf(a[2]) | ((unsigned)f2bf(a[3]) << 16);
    o.z = f2bf(a[4]) | ((unsigned)f2bf(a[5]) << 16);
    o.w = f2bf(a[6]) | ((unsigned)f2bf(a[7]) << 16);
    *reinterpret_cast<uint4*>(out + (size_t)node * F + j * 8) = o;
    return;
  }
  const float sd = sDst[node];
  float v[8];
#pragma unroll
  for (int k = 0; k < 8; ++k) v[k] = a[k] * sd + bias[j * 8 + k];
  if (EPI == 1) {
    float sn = snext[node];
    uint4 o;
    o.x = f2bf(v[0] * sn) | ((unsigned)f2bf(v[1] * sn) << 16);
    o.y = f2bf(v[2] * sn) | ((unsigned)f2bf(v[3] * sn) << 16);
    o.z = f2bf(v[4] * sn) | ((unsigned)f2bf(v[5] * sn) << 16);
    o.w = f2bf(v[6] * sn) | ((unsigned)f2bf(v[7] * sn) << 16);
    *reinterpret_cast<uint4*>(out + (size_t)node * F + j * 8) = o;
  }
  float4 s1, s2;
  s1.x = 1.0f / (1.0f + expf(-v[0]));
  s1.y = 1.0f / (1.0f + expf(-v[1]));
  s1.z = 1.0f / (1.0f + expf(-v[2]));
  s1.w = 1.0f / (1.0f + expf(-v[3]));
  s2.x = 1.0f / (1.0f + expf(-v[4]));
  s2.y = 1.0f / (1.0f + expf(-v[5]));
  s2.z = 1.0f / (1.0f + expf(-v[6]));
  s2.w = 1.0f / (1.0f + expf(-v[7]));
  *reinterpret_cast<float4*>(out2 + (size_t)node * F + j * 8) = s1;
  *reinterpret_cast<float4*>(out2 + (size_t)node * F + j * 8 + 4) = s2;
}

// ================= gemm8s: small-K GEMM (K = KT*32, KT<=8) — r10-proven ===========
template <int KT, int RELU>
__global__ __launch_bounds__(256) void gemm8s_kernel(
    const unsigned short* __restrict__ A, const unsigned short* __restrict__ Bt,
    unsigned short* __restrict__ C, int M, int Nreal, int NTn,
    const float* __restrict__ rowscale, const float* __restrict__ bias) {
  constexpr int K = KT * 32;
  constexpr int CPR = KT * 4;            // 16B chunks per LDS row
  constexpr int ROWB = CPR * 16;
  constexpr int TC = 64 * CPR;           // total chunks
  __shared__ __align__(16) char lds[64 * ROWB];

  const int sw = xcd_swizzle(blockIdx.x, gridDim.x);
  const int mg = sw / NTn, nt = sw - mg * NTn;  // n-fastest within XCD chunk
  const int tid = threadIdx.x;
  const int l = tid & 63, w = tid >> 6;
  const int lrow = l & 15, k16 = l >> 4;
  const int m0 = mg * 128 + w * 32, n0 = nt * 64;

  // ---- stage B[64][K] -> LDS (linear dest, inverse-swizzled source) ----
#pragma unroll
  for (int i = 0; i < TC / 256; ++i) {
    int c = i * 256 + tid;
    int row = c / CPR, lch = c % CPR;
    int gch = (lch & ~7) | ((lch & 7) ^ (row & 7));
    const unsigned short* gp = Bt + (size_t)(n0 + row) * K + gch * 8;
    __builtin_amdgcn_global_load_lds(
        (const __attribute__((address_space(1))) void*)gp,
        (__attribute__((address_space(3))) void*)(lds + (i * 256 + w * 64) * 16), 16, 0, 0);
  }

  // ---- issue ALL A-frags (independent of LDS) ----
  bf16x8 af[KT][2];
#pragma unroll
  for (int t = 0; t < KT; ++t)
#pragma unroll
    for (int mi = 0; mi < 2; ++mi)
      af[t][mi] = *reinterpret_cast<const bf16x8*>(
          A + (size_t)(m0 + mi * 16 + lrow) * K + t * 32 + k16 * 8);

  __syncthreads();  // single barrier: drains staging (and A-frags)

  // ---- pure LDS + MFMA burst ----
  f32x4 acc[2][4] = {};
#pragma unroll
  for (int t = 0; t < KT; ++t) {
    bf16x8 bf[4];
#pragma unroll
    for (int ni = 0; ni < 4; ++ni) {
      int row = ni * 16 + lrow;
      int ch = t * 4 + k16;
      int sc = (ch & ~7) | ((ch & 7) ^ (row & 7));
      bf[ni] = *reinterpret_cast<const bf16x8*>(lds + row * ROWB + sc * 16);
    }
#pragma unroll
    for (int mi = 0; mi < 2; ++mi)
#pragma unroll
      for (int ni = 0; ni < 4; ++ni)
        acc[mi][ni] = __builtin_amdgcn_mfma_f32_16x16x32_bf16(af[t][mi], bf[ni], acc[mi][ni], 0, 0, 0);
  }

  // ---- epilogue ----
#pragma unroll
  for (int mi = 0; mi < 2; ++mi) {
#pragma unroll
    for (int q = 0; q < 4; ++q) {
      int r = m0 + mi * 16 + k16 * 4 + q;
      if (r >= M) continue;
      float rs = rowscale[r];
#pragma unroll
      for (int ni = 0; ni < 4; ++ni) {
        int c = n0 + ni * 16 + lrow;
        if (c >= Nreal) continue;
        float v = acc[mi][ni][q] * rs + bias[c];
        if (RELU) v = fmaxf(v, 0.f);
        C[(size_t)r * Nreal + c] = f2bf(v);
      }
    }
  }
}

// ================= gemm8l: K=800 GEMM, B-tile staged in 2 LDS phases — r10-proven ==
template <int OUT_BF>
__global__ __launch_bounds__(256) void gemm8l_kernel(
    const unsigned short* __restrict__ A, const unsigned short* __restrict__ Bt,
    void* __restrict__ C, int M, int N, int NTn,
    const float* __restrict__ rowscale) {
  constexpr int K = 800, KPAD = 832;
  constexpr int CPR = 52;               // chunks per row per phase
  constexpr int ROWB = CPR * 16;
  __shared__ __align__(16) char lds[64 * ROWB];  // 52 KB

  const int sw = xcd_swizzle(blockIdx.x, gridDim.x);
  const int mg = sw / NTn, nt = sw - mg * NTn;
  const int tid = threadIdx.x;
  const int l = tid & 63, w = tid >> 6;
  const int lrow = l & 15, k16 = l >> 4;
  const int m0 = mg * 128 + w * 32, n0 = nt * 64;

  auto stage = [&](int phase) {
#pragma unroll
    for (int i = 0; i < 13; ++i) {  // 64*52/256
      int c = i * 256 + tid;
      int row = c / CPR, lch = c % CPR;
      int gch = phase * CPR + ((lch & ~3) | ((lch & 3) ^ (row & 3)));
      const unsigned short* gp = Bt + (size_t)(n0 + row) * KPAD + gch * 8;
      __builtin_amdgcn_global_load_lds(
          (const __attribute__((address_space(1))) void*)gp,
          (__attribute__((address_space(3))) void*)(lds + (i * 256 + w * 64) * 16), 16, 0, 0);
    }
  };

  f32x4 acc[2][4] = {};

  auto compute = [&](int t0, int t1, int phase) {
#pragma unroll 13
    for (int t = t0; t < t1; ++t) {
      bf16x8 a[2];
#pragma unroll
      for (int mi = 0; mi < 2; ++mi)
        a[mi] = *reinterpret_cast<const bf16x8*>(
            A + (size_t)(m0 + mi * 16 + lrow) * K + t * 32 + k16 * 8);
      bf16x8 bf[4];
#pragma unroll
      for (int ni = 0; ni < 4; ++ni) {
        int row = ni * 16 + lrow;
        int ch = t * 4 + k16 - phase * CPR;
        int sc = (ch & ~3) | ((ch & 3) ^ (row & 3));
        bf[ni] = *reinterpret_cast<const bf16x8*>(lds + row * ROWB + sc * 16);
      }
#pragma unroll
      for (int mi = 0; mi < 2; ++mi)
#pragma unroll
        for (int ni = 0; ni < 4; ++ni)
          acc[mi][ni] = __builtin_amdgcn_mfma_f32_16x16x32_bf16(a[mi], bf[ni], acc[mi][ni], 0, 0, 0);
    }
  };

  stage(0);
  __syncthreads();
  compute(0, 13, 0);      // chunks 0..51
  __syncthreads();        // all waves done with phase-0 LDS
  stage(1);
  __syncthreads();
  compute(13, 25, 1);     // chunks 52..99 (local 0..47)

#pragma unroll
  for (int mi = 0; mi < 2; ++mi) {
#pragma unroll
    for (int q = 0; q < 4; ++q) {
      int r = m0 + mi * 16 + k16 * 4 + q;
      if (r >= M) continue;
      float rs = rowscale[r];
#pragma unroll
      for (int ni = 0; ni < 4; ++ni) {
        int c = n0 + ni * 16 + lrow;
        float v = acc[mi][ni][q] * rs;
        if (OUT_BF) ((unsigned short*)C)[(size_t)r * N + c] = f2bf(v);
        else ((float*)C)[(size_t)r * N + c] = v;
      }
    }
  }
}

extern "C" void kernel_launch(void* const* d_in, const int* in_sizes, int n_in,
                              void* d_out, int out_size, void* d_ws, size_t ws_size,
                              hipStream_t stream) {
  const float* x  = (const float*)d_in[0];
  const int* src  = (const int*)d_in[1];
  const int* dst  = (const int*)d_in[2];
  const float* W1 = (const float*)d_in[3];
  const float* b1 = (const float*)d_in[4];
  const float* W2 = (const float*)d_in[5];
  const float* b2 = (const float*)d_in[6];
  const float* W3 = (const float*)d_in[7];
  const float* b3 = (const float*)d_in[8];
  const float* W4 = (const float*)d_in[9];
  const float* b4 = (const float*)d_in[10];

  float* out_enc = (float*)d_out;                  // [NN,128]
  float* out_dec = out_enc + (size_t)NN * 128;     // [NN,256]

  // ---- workspace layout (~82 MB) ----
  float* ns = (float*)d_ws;                        // [NN]
  float* nd = ns + NN;                             // [NN]
  unsigned short* xb  = (unsigned short*)(nd + NN);  // [NN*256]  bf16(x*ns)
  unsigned short* T2b = xb + (size_t)NN * 256;     // [NN*128] bf16 (gemm8l-L2 out)
  unsigned short* h2  = T2b + (size_t)NN * 128;    // [NN*128] bf16 (h2 * ns, L3 gather src)
  unsigned short* A1  = h2 + (size_t)NN * 128;     // [MROWS*256]
  unsigned short* A3  = A1 + (size_t)MROWS * 256;  // [MROWS*128]
  unsigned short* G4  = A3 + (size_t)MROWS * 128;  // [NN*256] bf16 (gemm8l-L4 out)
  unsigned short* H1  = G4 + (size_t)NN * 256;     // [MH*800] bf16 (gemm8s out)
  unsigned short* W1t = H1 + (size_t)MH * 800;     // [832*256]
  unsigned short* W2t = W1t + 832 * 256;           // [128*832]
  unsigned short* W3t = W2t + 128 * 832;           // [832*128]
  unsigned short* W4t = W3t + 832 * 128;           // [256*832]
  int* degs   = (int*)(W4t + 256 * 832);           // [NN]
  int* degd   = degs + NN;                         // [NN]
  int* cursor = degd + NN;                         // [NN]
  int* rowptr = cursor + NN;                       // [NN+1]
  int* col    = rowptr + NN + 1;                   // [NE]

  // ---- CSR build + norms (fused scan+norm) ----
  zero_kernel<<<(3 * NN / 4 + 255) / 256, 256, 0, stream>>>((int4*)degs, 3 * NN / 4);
  deg_count_kernel<<<(NE + 255) / 256, 256, 0, stream>>>(src, dst, degs, degd, NE);
  scan_norm_kernel<<<1, 1024, 0, stream>>>(degs, degd, rowptr, ns, nd, NN);
  csr_fill_kernel<<<(NE + 255) / 256, 256, 0, stream>>>(src, dst, rowptr, cursor, col, NE);

  // ---- weight conversion: one fused launch ----
  wt_convert_all_kernel<<<dim3(4, 2048), 256, 0, stream>>>(
      W1, W2, W3, W4, W1t, W2t, W3t, W4t);

  // grids
  const int GS = 157 * 13;   // gemm8s L1/L3 (Npad 832)
  const int GL2 = 157 * 2;   // gemm8l L2 (N=128)
  const int GL4 = 157 * 4;   // gemm8l L4 (N=256)

  // ---- L1: xb = bf16(x*ns); gather -> A1; gemm8s (K=256 -> 800) relu -> H1 ----
  scale_cvt_kernel<<<(NN * 32 + 255) / 256, 256, 0, stream>>>(x, ns, xb);
  gatherb_kernel<256, 0><<<(NN + 7) / 8, 256, 0, stream>>>(
      xb, rowptr, col, nullptr, nullptr, nullptr, A1, nullptr, NN);
  gemm8s_kernel<8, 1><<<GS, 256, 0, stream>>>(A1, W1t, H1, NN, 800, 13, nd, b1);

  // ---- L2: gemm8l (800 -> 128)*ns -> bf16 T2b; gather -> h2s=bf16(h2*ns) + sigmoid ----
  gemm8l_kernel<1><<<GL2, 256, 0, stream>>>(H1, W2t, T2b, NN, 128, 2, ns);
  gatherb_kernel<128, 1><<<(NN + 15) / 16, 256, 0, stream>>>(
      T2b, rowptr, col, nd, b2, ns, h2, out_enc, NN);

  // ---- L3: gather(h2s) -> A3; gemm8s (K=128 -> 800) relu -> H1 ----
  gatherb_kernel<128, 0><<<(NN + 15) / 16, 256, 0, stream>>>(
      h2, rowptr, col, nullptr, nullptr, nullptr, A3, nullptr, NN);
  gemm8s_kernel<4, 1><<<GS, 256, 0, stream>>>(A3, W3t, H1, NN, 800, 13, nd, b3);

  // ---- L4: gemm8l (800 -> 256)*ns -> bf16 G4; gather -> sigmoid(out_dec) ----
  gemm8l_kernel<1><<<GL4, 256, 0, stream>>>(H1, W4t, G4, NN, 256, 4, ns);
  gatherb_kernel<256, 2><<<(NN + 7) / 8, 256, 0, stream>>>(
      G4, rowptr, col, nd, b4, nullptr, nullptr, out_dec, NN);
}

// Round 14
// 253.103 us; speedup vs baseline: 1.2067x; 1.2067x over previous
//
#include <hip/hip_runtime.h>
#include <math.h>

constexpr int NN = 20000;   // nodes
constexpr int NE = 320000;  // edges
constexpr int MROWS = 20224; // A1/A3 row padding
constexpr int MH = 20096;   // H1 rows (157 groups of 128)
constexpr int SB = 79;      // scan blocks (79*256 >= NN)

typedef __bf16 bf16x8 __attribute__((ext_vector_type(8)));
typedef float f32x4 __attribute__((ext_vector_type(4)));

__device__ __forceinline__ unsigned short f2bf(float f) {
  unsigned int u = __float_as_uint(f);
  unsigned int r = (u + 0x7FFFu + ((u >> 16) & 1u)) >> 16;
  return (unsigned short)r;
}

// bijective XCD chunking (m204)
__device__ __forceinline__ int xcd_swizzle(int bid, int T) {
  int q = T >> 3, r = T & 7;
  int x = bid & 7, i = bid >> 3;
  return (x < r ? x * (q + 1) : r * (q + 1) + (x - r) * q) + i;
}

// ---------------- fast zero ----------------
__global__ __launch_bounds__(256) void zero_kernel(int4* __restrict__ p, int n4) {
  int i = blockIdx.x * 256 + threadIdx.x;
  if (i < n4) p[i] = make_int4(0, 0, 0, 0);
}

// ---------------- degree count ----------------
__global__ void deg_count_kernel(const int* __restrict__ src, const int* __restrict__ dst,
                                 int* __restrict__ degs, int* __restrict__ degd, int nE) {
  int e = blockIdx.x * blockDim.x + threadIdx.x;
  if (e < nE) {
    atomicAdd(degs + src[e], 1);
    atomicAdd(degd + dst[e], 1);
  }
}

// ---------------- scan phase B: norms + block-local exclusive scan + block sums ----
__global__ __launch_bounds__(256) void pscan_norm_kernel(
    const int* __restrict__ degs, const int* __restrict__ degd,
    int* __restrict__ pscan, int* __restrict__ bsum,
    float* __restrict__ ns, float* __restrict__ nd, int n) {
  __shared__ int s[256];
  int t = threadIdx.x;
  int idx = blockIdx.x * 256 + t;
  int val = 0;
  if (idx < n) {
    int dd = degd[idx];
    val = dd;
    ns[idx] = rsqrtf(fmaxf((float)degs[idx], 1.0f));
    nd[idx] = rsqrtf(fmaxf((float)dd, 1.0f));
  }
  s[t] = val;
  __syncthreads();
#pragma unroll
  for (int off = 1; off < 256; off <<= 1) {
    int v = (t >= off) ? s[t - off] : 0;
    __syncthreads();
    s[t] += v;
    __syncthreads();
  }
  if (idx < n) pscan[idx] = s[t] - val;  // exclusive within block
  if (t == 255) bsum[blockIdx.x] = s[255];
}

// ---------------- scan phase C: exclusive scan of block sums (SB <= 128) ----------
__global__ __launch_bounds__(128) void scan_off_kernel(
    const int* __restrict__ bsum, int* __restrict__ boff, int nb) {
  __shared__ int s[128];
  int t = threadIdx.x;
  int val = (t < nb) ? bsum[t] : 0;
  s[t] = val;
  __syncthreads();
#pragma unroll
  for (int off = 1; off < 128; off <<= 1) {
    int v = (t >= off) ? s[t - off] : 0;
    __syncthreads();
    s[t] += v;
    __syncthreads();
  }
  if (t < nb) boff[t] = s[t] - val;
}

// ---------------- scan phase D: rowptr = pscan + boff; rowptr[n] = NE -------------
__global__ __launch_bounds__(256) void rowptr_fix_kernel(
    const int* __restrict__ pscan, const int* __restrict__ boff,
    int* __restrict__ rowptr, int n) {
  int idx = blockIdx.x * 256 + threadIdx.x;
  if (idx < n) rowptr[idx] = pscan[idx] + boff[blockIdx.x];
  if (idx == 0) rowptr[n] = NE;
}

// ---------------- CSR fill ----------------
__global__ void csr_fill_kernel(const int* __restrict__ src, const int* __restrict__ dst,
                                const int* __restrict__ rowptr, int* __restrict__ cursor,
                                int* __restrict__ col, int nE) {
  int e = blockIdx.x * blockDim.x + threadIdx.x;
  if (e < nE) {
    int d = dst[e];
    int p = atomicAdd(cursor + d, 1);
    col[rowptr[d] + p] = src[e];
  }
}

// ---------------- fused weight convert: all 4 Wt[Npad][Kpad] in one launch ---------
__global__ __launch_bounds__(256) void wt_convert_all_kernel(
    const float* __restrict__ W1, const float* __restrict__ W2,
    const float* __restrict__ W3, const float* __restrict__ W4,
    unsigned short* __restrict__ W1t, unsigned short* __restrict__ W2t,
    unsigned short* __restrict__ W3t, unsigned short* __restrict__ W4t) {
  int n = blockIdx.y;
  int k = blockIdx.x * 256 + threadIdx.x;
  const float* W; unsigned short* Wt; int K, N, Kpad;
  if (n < 832)       { W = W1; Wt = W1t; K = 256; N = 800; Kpad = 256; }
  else if (n < 960)  { n -= 832;  W = W2; Wt = W2t; K = 800; N = 128; Kpad = 832; }
  else if (n < 1792) { n -= 960;  W = W3; Wt = W3t; K = 128; N = 800; Kpad = 128; }
  else               { n -= 1792; W = W4; Wt = W4t; K = 800; N = 256; Kpad = 832; }
  if (k >= Kpad) return;
  float v = (n < N && k < K) ? W[(size_t)k * N + n] : 0.f;
  Wt[(size_t)n * Kpad + k] = f2bf(v);
}

// ---------------- xb = bf16(x * ns[row]) pre-pass ----------------
__global__ __launch_bounds__(256) void scale_cvt_kernel(
    const float* __restrict__ x, const float* __restrict__ ns,
    unsigned short* __restrict__ xb) {
  int t = blockIdx.x * 256 + threadIdx.x;
  if (t >= NN * 32) return;
  int node = t >> 5;
  float sc = ns[node];
  float4 v1 = reinterpret_cast<const float4*>(x)[t * 2];
  float4 v2 = reinterpret_cast<const float4*>(x)[t * 2 + 1];
  uint4 o;
  o.x = f2bf(v1.x * sc) | ((unsigned)f2bf(v1.y * sc) << 16);
  o.y = f2bf(v1.z * sc) | ((unsigned)f2bf(v1.w * sc) << 16);
  o.z = f2bf(v2.x * sc) | ((unsigned)f2bf(v2.y * sc) << 16);
  o.w = f2bf(v2.z * sc) | ((unsigned)f2bf(v2.w * sc) << 16);
  reinterpret_cast<uint4*>(xb)[t] = o;
}

// ---------------- bf16 CSR gather (edge loop unrolled x2) ----------------
template <int F, int EPI>
__global__ __launch_bounds__(256) void gatherb_kernel(
    const unsigned short* __restrict__ in, const int* __restrict__ rowptr,
    const int* __restrict__ col, const float* __restrict__ sDst,
    const float* __restrict__ bias, const float* __restrict__ snext,
    unsigned short* __restrict__ out, float* __restrict__ out2, int n) {
  constexpr int LPN = F / 8;
  constexpr int NPB = 256 / LPN;
  const int tid = threadIdx.x;
  const int node = blockIdx.x * NPB + tid / LPN;
  const int j = tid % LPN;
  if (node >= n) return;
  const int e0 = rowptr[node], e1 = rowptr[node + 1];
  float a[8] = {0.f, 0.f, 0.f, 0.f, 0.f, 0.f, 0.f, 0.f};
  int e = e0;
  for (; e + 1 < e1; e += 2) {
    int c0 = col[e], c1 = col[e + 1];
    uint4 u0 = *reinterpret_cast<const uint4*>(in + (size_t)c0 * F + j * 8);
    uint4 u1 = *reinterpret_cast<const uint4*>(in + (size_t)c1 * F + j * 8);
    a[0] += __uint_as_float(u0.x << 16);
    a[1] += __uint_as_float(u0.x & 0xffff0000u);
    a[2] += __uint_as_float(u0.y << 16);
    a[3] += __uint_as_float(u0.y & 0xffff0000u);
    a[4] += __uint_as_float(u0.z << 16);
    a[5] += __uint_as_float(u0.z & 0xffff0000u);
    a[6] += __uint_as_float(u0.w << 16);
    a[7] += __uint_as_float(u0.w & 0xffff0000u);
    a[0] += __uint_as_float(u1.x << 16);
    a[1] += __uint_as_float(u1.x & 0xffff0000u);
    a[2] += __uint_as_float(u1.y << 16);
    a[3] += __uint_as_float(u1.y & 0xffff0000u);
    a[4] += __uint_as_float(u1.z << 16);
    a[5] += __uint_as_float(u1.z & 0xffff0000u);
    a[6] += __uint_as_float(u1.w << 16);
    a[7] += __uint_as_float(u1.w & 0xffff0000u);
  }
  if (e < e1) {
    int c = col[e];
    uint4 u = *reinterpret_cast<const uint4*>(in + (size_t)c * F + j * 8);
    a[0] += __uint_as_float(u.x << 16);
    a[1] += __uint_as_float(u.x & 0xffff0000u);
    a[2] += __uint_as_float(u.y << 16);
    a[3] += __uint_as_float(u.y & 0xffff0000u);
    a[4] += __uint_as_float(u.z << 16);
    a[5] += __uint_as_float(u.z & 0xffff0000u);
    a[6] += __uint_as_float(u.w << 16);
    a[7] += __uint_as_float(u.w & 0xffff0000u);
  }
  if (EPI == 0) {
    uint4 o;
    o.x = f2bf(a[0]) | ((unsigned)f2bf(a[1]) << 16);
    o.y = f2bf(a[2]) | ((unsigned)f2bf(a[3]) << 16);
    o.z = f2bf(a[4]) | ((unsigned)f2bf(a[5]) << 16);
    o.w = f2bf(a[6]) | ((unsigned)f2bf(a[7]) << 16);
    *reinterpret_cast<uint4*>(out + (size_t)node * F + j * 8) = o;
    return;
  }
  const float sd = sDst[node];
  float v[8];
#pragma unroll
  for (int k = 0; k < 8; ++k) v[k] = a[k] * sd + bias[j * 8 + k];
  if (EPI == 1) {
    float sn = snext[node];
    uint4 o;
    o.x = f2bf(v[0] * sn) | ((unsigned)f2bf(v[1] * sn) << 16);
    o.y = f2bf(v[2] * sn) | ((unsigned)f2bf(v[3] * sn) << 16);
    o.z = f2bf(v[4] * sn) | ((unsigned)f2bf(v[5] * sn) << 16);
    o.w = f2bf(v[6] * sn) | ((unsigned)f2bf(v[7] * sn) << 16);
    *reinterpret_cast<uint4*>(out + (size_t)node * F + j * 8) = o;
  }
  float4 s1, s2;
  s1.x = 1.0f / (1.0f + expf(-v[0]));
  s1.y = 1.0f / (1.0f + expf(-v[1]));
  s1.z = 1.0f / (1.0f + expf(-v[2]));
  s1.w = 1.0f / (1.0f + expf(-v[3]));
  s2.x = 1.0f / (1.0f + expf(-v[4]));
  s2.y = 1.0f / (1.0f + expf(-v[5]));
  s2.z = 1.0f / (1.0f + expf(-v[6]));
  s2.w = 1.0f / (1.0f + expf(-v[7]));
  *reinterpret_cast<float4*>(out2 + (size_t)node * F + j * 8) = s1;
  *reinterpret_cast<float4*>(out2 + (size_t)node * F + j * 8 + 4) = s2;
}

// ================= gemm8s: small-K GEMM (K = KT*32, KT<=8) — r10-proven ===========
template <int KT, int RELU>
__global__ __launch_bounds__(256) void gemm8s_kernel(
    const unsigned short* __restrict__ A, const unsigned short* __restrict__ Bt,
    unsigned short* __restrict__ C, int M, int Nreal, int NTn,
    const float* __restrict__ rowscale, const float* __restrict__ bias) {
  constexpr int K = KT * 32;
  constexpr int CPR = KT * 4;
  constexpr int ROWB = CPR * 16;
  constexpr int TC = 64 * CPR;
  __shared__ __align__(16) char lds[64 * ROWB];

  const int sw = xcd_swizzle(blockIdx.x, gridDim.x);
  const int mg = sw / NTn, nt = sw - mg * NTn;
  const int tid = threadIdx.x;
  const int l = tid & 63, w = tid >> 6;
  const int lrow = l & 15, k16 = l >> 4;
  const int m0 = mg * 128 + w * 32, n0 = nt * 64;

#pragma unroll
  for (int i = 0; i < TC / 256; ++i) {
    int c = i * 256 + tid;
    int row = c / CPR, lch = c % CPR;
    int gch = (lch & ~7) | ((lch & 7) ^ (row & 7));
    const unsigned short* gp = Bt + (size_t)(n0 + row) * K + gch * 8;
    __builtin_amdgcn_global_load_lds(
        (const __attribute__((address_space(1))) void*)gp,
        (__attribute__((address_space(3))) void*)(lds + (i * 256 + w * 64) * 16), 16, 0, 0);
  }

  bf16x8 af[KT][2];
#pragma unroll
  for (int t = 0; t < KT; ++t)
#pragma unroll
    for (int mi = 0; mi < 2; ++mi)
      af[t][mi] = *reinterpret_cast<const bf16x8*>(
          A + (size_t)(m0 + mi * 16 + lrow) * K + t * 32 + k16 * 8);

  __syncthreads();

  f32x4 acc[2][4] = {};
#pragma unroll
  for (int t = 0; t < KT; ++t) {
    bf16x8 bf[4];
#pragma unroll
    for (int ni = 0; ni < 4; ++ni) {
      int row = ni * 16 + lrow;
      int ch = t * 4 + k16;
      int sc = (ch & ~7) | ((ch & 7) ^ (row & 7));
      bf[ni] = *reinterpret_cast<const bf16x8*>(lds + row * ROWB + sc * 16);
    }
#pragma unroll
    for (int mi = 0; mi < 2; ++mi)
#pragma unroll
      for (int ni = 0; ni < 4; ++ni)
        acc[mi][ni] = __builtin_amdgcn_mfma_f32_16x16x32_bf16(af[t][mi], bf[ni], acc[mi][ni], 0, 0, 0);
  }

#pragma unroll
  for (int mi = 0; mi < 2; ++mi) {
#pragma unroll
    for (int q = 0; q < 4; ++q) {
      int r = m0 + mi * 16 + k16 * 4 + q;
      if (r >= M) continue;
      float rs = rowscale[r];
#pragma unroll
      for (int ni = 0; ni < 4; ++ni) {
        int c = n0 + ni * 16 + lrow;
        if (c >= Nreal) continue;
        float v = acc[mi][ni][q] * rs + bias[c];
        if (RELU) v = fmaxf(v, 0.f);
        C[(size_t)r * Nreal + c] = f2bf(v);
      }
    }
  }
}

// ================= gemm8l: K=800 GEMM, B-tile staged in 2 LDS phases — r10-proven ==
template <int OUT_BF>
__global__ __launch_bounds__(256) void gemm8l_kernel(
    const unsigned short* __restrict__ A, const unsigned short* __restrict__ Bt,
    void* __restrict__ C, int M, int N, int NTn,
    const float* __restrict__ rowscale) {
  constexpr int K = 800, KPAD = 832;
  constexpr int CPR = 52;
  constexpr int ROWB = CPR * 16;
  __shared__ __align__(16) char lds[64 * ROWB];

  const int sw = xcd_swizzle(blockIdx.x, gridDim.x);
  const int mg = sw / NTn, nt = sw - mg * NTn;
  const int tid = threadIdx.x;
  const int l = tid & 63, w = tid >> 6;
  const int lrow = l & 15, k16 = l >> 4;
  const int m0 = mg * 128 + w * 32, n0 = nt * 64;

  auto stage = [&](int phase) {
#pragma unroll
    for (int i = 0; i < 13; ++i) {
      int c = i * 256 + tid;
      int row = c / CPR, lch = c % CPR;
      int gch = phase * CPR + ((lch & ~3) | ((lch & 3) ^ (row & 3)));
      const unsigned short* gp = Bt + (size_t)(n0 + row) * KPAD + gch * 8;
      __builtin_amdgcn_global_load_lds(
          (const __attribute__((address_space(1))) void*)gp,
          (__attribute__((address_space(3))) void*)(lds + (i * 256 + w * 64) * 16), 16, 0, 0);
    }
  };

  f32x4 acc[2][4] = {};

  auto compute = [&](int t0, int t1, int phase) {
#pragma unroll 13
    for (int t = t0; t < t1; ++t) {
      bf16x8 a[2];
#pragma unroll
      for (int mi = 0; mi < 2; ++mi)
        a[mi] = *reinterpret_cast<const bf16x8*>(
            A + (size_t)(m0 + mi * 16 + lrow) * K + t * 32 + k16 * 8);
      bf16x8 bf[4];
#pragma unroll
      for (int ni = 0; ni < 4; ++ni) {
        int row = ni * 16 + lrow;
        int ch = t * 4 + k16 - phase * CPR;
        int sc = (ch & ~3) | ((ch & 3) ^ (row & 3));
        bf[ni] = *reinterpret_cast<const bf16x8*>(lds + row * ROWB + sc * 16);
      }
#pragma unroll
      for (int mi = 0; mi < 2; ++mi)
#pragma unroll
        for (int ni = 0; ni < 4; ++ni)
          acc[mi][ni] = __builtin_amdgcn_mfma_f32_16x16x32_bf16(a[mi], bf[ni], acc[mi][ni], 0, 0, 0);
    }
  };

  stage(0);
  __syncthreads();
  compute(0, 13, 0);
  __syncthreads();
  stage(1);
  __syncthreads();
  compute(13, 25, 1);

#pragma unroll
  for (int mi = 0; mi < 2; ++mi) {
#pragma unroll
    for (int q = 0; q < 4; ++q) {
      int r = m0 + mi * 16 + k16 * 4 + q;
      if (r >= M) continue;
      float rs = rowscale[r];
#pragma unroll
      for (int ni = 0; ni < 4; ++ni) {
        int c = n0 + ni * 16 + lrow;
        float v = acc[mi][ni][q] * rs;
        if (OUT_BF) ((unsigned short*)C)[(size_t)r * N + c] = f2bf(v);
        else ((float*)C)[(size_t)r * N + c] = v;
      }
    }
  }
}

extern "C" void kernel_launch(void* const* d_in, const int* in_sizes, int n_in,
                              void* d_out, int out_size, void* d_ws, size_t ws_size,
                              hipStream_t stream) {
  const float* x  = (const float*)d_in[0];
  const int* src  = (const int*)d_in[1];
  const int* dst  = (const int*)d_in[2];
  const float* W1 = (const float*)d_in[3];
  const float* b1 = (const float*)d_in[4];
  const float* W2 = (const float*)d_in[5];
  const float* b2 = (const float*)d_in[6];
  const float* W3 = (const float*)d_in[7];
  const float* b3 = (const float*)d_in[8];
  const float* W4 = (const float*)d_in[9];
  const float* b4 = (const float*)d_in[10];

  float* out_enc = (float*)d_out;                  // [NN,128]
  float* out_dec = out_enc + (size_t)NN * 128;     // [NN,256]

  // ---- workspace layout (~82 MB) ----
  float* ns = (float*)d_ws;                        // [NN]
  float* nd = ns + NN;                             // [NN]
  unsigned short* xb  = (unsigned short*)(nd + NN);  // [NN*256]
  unsigned short* T2b = xb + (size_t)NN * 256;     // [NN*128] bf16
  unsigned short* h2  = T2b + (size_t)NN * 128;    // [NN*128] bf16
  unsigned short* A1  = h2 + (size_t)NN * 128;     // [MROWS*256]
  unsigned short* A3  = A1 + (size_t)MROWS * 256;  // [MROWS*128]
  unsigned short* G4  = A3 + (size_t)MROWS * 128;  // [NN*256]
  unsigned short* H1  = G4 + (size_t)NN * 256;     // [MH*800]
  unsigned short* W1t = H1 + (size_t)MH * 800;     // [832*256]
  unsigned short* W2t = W1t + 832 * 256;           // [128*832]
  unsigned short* W3t = W2t + 128 * 832;           // [832*128]
  unsigned short* W4t = W3t + 832 * 128;           // [256*832]
  int* degs   = (int*)(W4t + 256 * 832);           // [NN]
  int* degd   = degs + NN;                         // [NN]
  int* cursor = degd + NN;                         // [NN]
  int* rowptr = cursor + NN;                       // [NN+1]
  int* col    = rowptr + NN + 1;                   // [NE]
  int* pscan  = col + NE;                          // [NN]
  int* bsum   = pscan + NN;                        // [SB]
  int* boff   = bsum + SB;                         // [SB]

  // ---- CSR build + norms (3-phase parallel scan) ----
  zero_kernel<<<(3 * NN / 4 + 255) / 256, 256, 0, stream>>>((int4*)degs, 3 * NN / 4);
  deg_count_kernel<<<(NE + 255) / 256, 256, 0, stream>>>(src, dst, degs, degd, NE);
  pscan_norm_kernel<<<SB, 256, 0, stream>>>(degs, degd, pscan, bsum, ns, nd, NN);
  scan_off_kernel<<<1, 128, 0, stream>>>(bsum, boff, SB);
  rowptr_fix_kernel<<<SB, 256, 0, stream>>>(pscan, boff, rowptr, NN);
  csr_fill_kernel<<<(NE + 255) / 256, 256, 0, stream>>>(src, dst, rowptr, cursor, col, NE);

  // ---- weight conversion: one fused launch ----
  wt_convert_all_kernel<<<dim3(4, 2048), 256, 0, stream>>>(
      W1, W2, W3, W4, W1t, W2t, W3t, W4t);

  // grids
  const int GS = 157 * 13;   // gemm8s L1/L3 (Npad 832)
  const int GL2 = 157 * 2;   // gemm8l L2 (N=128)
  const int GL4 = 157 * 4;   // gemm8l L4 (N=256)

  // ---- L1: xb = bf16(x*ns); gather -> A1; gemm8s (K=256 -> 800) relu -> H1 ----
  scale_cvt_kernel<<<(NN * 32 + 255) / 256, 256, 0, stream>>>(x, ns, xb);
  gatherb_kernel<256, 0><<<(NN + 7) / 8, 256, 0, stream>>>(
      xb, rowptr, col, nullptr, nullptr, nullptr, A1, nullptr, NN);
  gemm8s_kernel<8, 1><<<GS, 256, 0, stream>>>(A1, W1t, H1, NN, 800, 13, nd, b1);

  // ---- L2: gemm8l (800 -> 128)*ns -> bf16 T2b; gather -> h2s + sigmoid(out_enc) ----
  gemm8l_kernel<1><<<GL2, 256, 0, stream>>>(H1, W2t, T2b, NN, 128, 2, ns);
  gatherb_kernel<128, 1><<<(NN + 15) / 16, 256, 0, stream>>>(
      T2b, rowptr, col, nd, b2, ns, h2, out_enc, NN);

  // ---- L3: gather(h2s) -> A3; gemm8s (K=128 -> 800) relu -> H1 ----
  gatherb_kernel<128, 0><<<(NN + 15) / 16, 256, 0, stream>>>(
      h2, rowptr, col, nullptr, nullptr, nullptr, A3, nullptr, NN);
  gemm8s_kernel<4, 1><<<GS, 256, 0, stream>>>(A3, W3t, H1, NN, 800, 13, nd, b3);

  // ---- L4: gemm8l (800 -> 256)*ns -> bf16 G4; gather -> sigmoid(out_dec) ----
  gemm8l_kernel<1><<<GL4, 256, 0, stream>>>(H1, W4t, G4, NN, 256, 4, ns);
  gatherb_kernel<256, 2><<<(NN + 7) / 8, 256, 0, stream>>>(
      G4, rowptr, col, nd, b4, nullptr, nullptr, out_dec, NN);
}

// Round 15
// 247.273 us; speedup vs baseline: 1.2351x; 1.0236x over previous
//
#include <hip/hip_runtime.h>
#include <math.h>

constexpr int NN = 20000;   // nodes
constexpr int NE = 320000;  // edges
constexpr int MROWS = 20224; // A1/A3 row padding
constexpr int MH = 20096;   // H1 rows (157 groups of 128)
constexpr int SB = 79;      // scan blocks (79*256 >= NN)

typedef __bf16 bf16x8 __attribute__((ext_vector_type(8)));
typedef float f32x4 __attribute__((ext_vector_type(4)));

__device__ __forceinline__ unsigned short f2bf(float f) {
  unsigned int u = __float_as_uint(f);
  unsigned int r = (u + 0x7FFFu + ((u >> 16) & 1u)) >> 16;
  return (unsigned short)r;
}

// bijective XCD chunking (m204)
__device__ __forceinline__ int xcd_swizzle(int bid, int T) {
  int q = T >> 3, r = T & 7;
  int x = bid & 7, i = bid >> 3;
  return (x < r ? x * (q + 1) : r * (q + 1) + (x - r) * q) + i;
}

// ---------------- fast zero ----------------
__global__ __launch_bounds__(256) void zero_kernel(int4* __restrict__ p, int n4) {
  int i = blockIdx.x * 256 + threadIdx.x;
  if (i < n4) p[i] = make_int4(0, 0, 0, 0);
}

// ---------------- degree count ----------------
__global__ void deg_count_kernel(const int* __restrict__ src, const int* __restrict__ dst,
                                 int* __restrict__ degs, int* __restrict__ degd, int nE) {
  int e = blockIdx.x * blockDim.x + threadIdx.x;
  if (e < nE) {
    atomicAdd(degs + src[e], 1);
    atomicAdd(degd + dst[e], 1);
  }
}

// ---------------- scan phase B: norms + block-local exclusive scan + block sums ----
__global__ __launch_bounds__(256) void pscan_norm_kernel(
    const int* __restrict__ degs, const int* __restrict__ degd,
    int* __restrict__ pscan, int* __restrict__ bsum,
    float* __restrict__ ns, float* __restrict__ nd, int n) {
  __shared__ int s[256];
  int t = threadIdx.x;
  int idx = blockIdx.x * 256 + t;
  int val = 0;
  if (idx < n) {
    int dd = degd[idx];
    val = dd;
    ns[idx] = rsqrtf(fmaxf((float)degs[idx], 1.0f));
    nd[idx] = rsqrtf(fmaxf((float)dd, 1.0f));
  }
  s[t] = val;
  __syncthreads();
#pragma unroll
  for (int off = 1; off < 256; off <<= 1) {
    int v = (t >= off) ? s[t - off] : 0;
    __syncthreads();
    s[t] += v;
    __syncthreads();
  }
  if (idx < n) pscan[idx] = s[t] - val;  // exclusive within block
  if (t == 255) bsum[blockIdx.x] = s[255];
}

// ---------------- scan phase C+D fused: rowptr = pscan + offset(block) -------------
// Each block redundantly scans bsum[SB] (tiny) -> no separate offset kernel.
__global__ __launch_bounds__(256) void rowptr_fix_kernel(
    const int* __restrict__ pscan, const int* __restrict__ bsum,
    int* __restrict__ rowptr, int n) {
  __shared__ int s[128];
  int t = threadIdx.x;
  if (t < 128) s[t] = (t < SB) ? bsum[t] : 0;
  __syncthreads();
#pragma unroll
  for (int off = 1; off < 128; off <<= 1) {
    int v = (t < 128 && t >= off) ? s[t - off] : 0;
    __syncthreads();
    if (t < 128) s[t] += v;
    __syncthreads();
  }
  int idx = blockIdx.x * 256 + t;
  int boff = (blockIdx.x == 0) ? 0 : s[blockIdx.x - 1];  // inclusive scan -> prefix
  if (idx < n) rowptr[idx] = pscan[idx] + boff;
  if (idx == 0) rowptr[n] = NE;
}

// ---------------- CSR fill ----------------
__global__ void csr_fill_kernel(const int* __restrict__ src, const int* __restrict__ dst,
                                const int* __restrict__ rowptr, int* __restrict__ cursor,
                                int* __restrict__ col, int nE) {
  int e = blockIdx.x * blockDim.x + threadIdx.x;
  if (e < nE) {
    int d = dst[e];
    int p = atomicAdd(cursor + d, 1);
    col[rowptr[d] + p] = src[e];
  }
}

// ---------------- fused weight convert: all 4 Wt[Npad][Kpad] in one launch ---------
__global__ __launch_bounds__(256) void wt_convert_all_kernel(
    const float* __restrict__ W1, const float* __restrict__ W2,
    const float* __restrict__ W3, const float* __restrict__ W4,
    unsigned short* __restrict__ W1t, unsigned short* __restrict__ W2t,
    unsigned short* __restrict__ W3t, unsigned short* __restrict__ W4t) {
  int n = blockIdx.y;
  int k = blockIdx.x * 256 + threadIdx.x;
  const float* W; unsigned short* Wt; int K, N, Kpad;
  if (n < 832)       { W = W1; Wt = W1t; K = 256; N = 800; Kpad = 256; }
  else if (n < 960)  { n -= 832;  W = W2; Wt = W2t; K = 800; N = 128; Kpad = 832; }
  else if (n < 1792) { n -= 960;  W = W3; Wt = W3t; K = 128; N = 800; Kpad = 128; }
  else               { n -= 1792; W = W4; Wt = W4t; K = 800; N = 256; Kpad = 832; }
  if (k >= Kpad) return;
  float v = (n < N && k < K) ? W[(size_t)k * N + n] : 0.f;
  Wt[(size_t)n * Kpad + k] = f2bf(v);
}

// ---------------- xb = bf16(x * ns[row]) pre-pass ----------------
__global__ __launch_bounds__(256) void scale_cvt_kernel(
    const float* __restrict__ x, const float* __restrict__ ns,
    unsigned short* __restrict__ xb) {
  int t = blockIdx.x * 256 + threadIdx.x;
  if (t >= NN * 32) return;
  int node = t >> 5;
  float sc = ns[node];
  float4 v1 = reinterpret_cast<const float4*>(x)[t * 2];
  float4 v2 = reinterpret_cast<const float4*>(x)[t * 2 + 1];
  uint4 o;
  o.x = f2bf(v1.x * sc) | ((unsigned)f2bf(v1.y * sc) << 16);
  o.y = f2bf(v1.z * sc) | ((unsigned)f2bf(v1.w * sc) << 16);
  o.z = f2bf(v2.x * sc) | ((unsigned)f2bf(v2.y * sc) << 16);
  o.w = f2bf(v2.z * sc) | ((unsigned)f2bf(v2.w * sc) << 16);
  reinterpret_cast<uint4*>(xb)[t] = o;
}

// ---------------- bf16 CSR gather (edge loop unrolled x2) ----------------
template <int F, int EPI>
__global__ __launch_bounds__(256) void gatherb_kernel(
    const unsigned short* __restrict__ in, const int* __restrict__ rowptr,
    const int* __restrict__ col, const float* __restrict__ sDst,
    const float* __restrict__ bias, const float* __restrict__ snext,
    unsigned short* __restrict__ out, float* __restrict__ out2, int n) {
  constexpr int LPN = F / 8;
  constexpr int NPB = 256 / LPN;
  const int tid = threadIdx.x;
  const int node = blockIdx.x * NPB + tid / LPN;
  const int j = tid % LPN;
  if (node >= n) return;
  const int e0 = rowptr[node], e1 = rowptr[node + 1];
  float a[8] = {0.f, 0.f, 0.f, 0.f, 0.f, 0.f, 0.f, 0.f};
  int e = e0;
  for (; e + 1 < e1; e += 2) {
    int c0 = col[e], c1 = col[e + 1];
    uint4 u0 = *reinterpret_cast<const uint4*>(in + (size_t)c0 * F + j * 8);
    uint4 u1 = *reinterpret_cast<const uint4*>(in + (size_t)c1 * F + j * 8);
    a[0] += __uint_as_float(u0.x << 16);
    a[1] += __uint_as_float(u0.x & 0xffff0000u);
    a[2] += __uint_as_float(u0.y << 16);
    a[3] += __uint_as_float(u0.y & 0xffff0000u);
    a[4] += __uint_as_float(u0.z << 16);
    a[5] += __uint_as_float(u0.z & 0xffff0000u);
    a[6] += __uint_as_float(u0.w << 16);
    a[7] += __uint_as_float(u0.w & 0xffff0000u);
    a[0] += __uint_as_float(u1.x << 16);
    a[1] += __uint_as_float(u1.x & 0xffff0000u);
    a[2] += __uint_as_float(u1.y << 16);
    a[3] += __uint_as_float(u1.y & 0xffff0000u);
    a[4] += __uint_as_float(u1.z << 16);
    a[5] += __uint_as_float(u1.z & 0xffff0000u);
    a[6] += __uint_as_float(u1.w << 16);
    a[7] += __uint_as_float(u1.w & 0xffff0000u);
  }
  if (e < e1) {
    int c = col[e];
    uint4 u = *reinterpret_cast<const uint4*>(in + (size_t)c * F + j * 8);
    a[0] += __uint_as_float(u.x << 16);
    a[1] += __uint_as_float(u.x & 0xffff0000u);
    a[2] += __uint_as_float(u.y << 16);
    a[3] += __uint_as_float(u.y & 0xffff0000u);
    a[4] += __uint_as_float(u.z << 16);
    a[5] += __uint_as_float(u.z & 0xffff0000u);
    a[6] += __uint_as_float(u.w << 16);
    a[7] += __uint_as_float(u.w & 0xffff0000u);
  }
  if (EPI == 0) {
    uint4 o;
    o.x = f2bf(a[0]) | ((unsigned)f2bf(a[1]) << 16);
    o.y = f2bf(a[2]) | ((unsigned)f2bf(a[3]) << 16);
    o.z = f2bf(a[4]) | ((unsigned)f2bf(a[5]) << 16);
    o.w = f2bf(a[6]) | ((unsigned)f2bf(a[7]) << 16);
    *reinterpret_cast<uint4*>(out + (size_t)node * F + j * 8) = o;
    return;
  }
  const float sd = sDst[node];
  float v[8];
#pragma unroll
  for (int k = 0; k < 8; ++k) v[k] = a[k] * sd + bias[j * 8 + k];
  if (EPI == 1) {
    float sn = snext[node];
    uint4 o;
    o.x = f2bf(v[0] * sn) | ((unsigned)f2bf(v[1] * sn) << 16);
    o.y = f2bf(v[2] * sn) | ((unsigned)f2bf(v[3] * sn) << 16);
    o.z = f2bf(v[4] * sn) | ((unsigned)f2bf(v[5] * sn) << 16);
    o.w = f2bf(v[6] * sn) | ((unsigned)f2bf(v[7] * sn) << 16);
    *reinterpret_cast<uint4*>(out + (size_t)node * F + j * 8) = o;
  }
  float4 s1, s2;
  s1.x = 1.0f / (1.0f + expf(-v[0]));
  s1.y = 1.0f / (1.0f + expf(-v[1]));
  s1.z = 1.0f / (1.0f + expf(-v[2]));
  s1.w = 1.0f / (1.0f + expf(-v[3]));
  s2.x = 1.0f / (1.0f + expf(-v[4]));
  s2.y = 1.0f / (1.0f + expf(-v[5]));
  s2.z = 1.0f / (1.0f + expf(-v[6]));
  s2.w = 1.0f / (1.0f + expf(-v[7]));
  *reinterpret_cast<float4*>(out2 + (size_t)node * F + j * 8) = s1;
  *reinterpret_cast<float4*>(out2 + (size_t)node * F + j * 8 + 4) = s2;
}

// ================= gemm9f: FUSED L1+L2 GEMM =======================================
// Per 128-row m-group (157 blocks, 4 waves x 32 rows):
//   H1tile = relu(nd[r]*(A1band @ W1panel^T) + b1)   (bf16, per-wave LDS tile)
//   acc2  += H1tile @ W2slice^T                       (k-slice = n-tile cols)
//   T2b[r][c] = bf16(acc2 * ns[r])
// Eliminates the 32MB H1 write + re-read. Rows independent across both GEMMs ->
// per-wave H1 tile needs NO barrier (same-wave LDS RAW tracked by lgkmcnt).
// LDS: W1panel dbuf 2x32KB + W2slice dbuf 2x16KB + 4x4KB H1 tiles = 112KB.
__global__ __launch_bounds__(256) void gemm9f_kernel(
    const unsigned short* __restrict__ A,    // A1 [MROWS][256] bf16
    const unsigned short* __restrict__ W1t,  // [832][256] bf16
    const unsigned short* __restrict__ W2t,  // [128][832] bf16
    unsigned short* __restrict__ T2b,        // [NN][128] bf16 out
    int M, const float* __restrict__ nd, const float* __restrict__ ns,
    const float* __restrict__ b1) {
  __shared__ __align__(16) char lds[112 * 1024];
  const int tid = threadIdx.x;
  const int l = tid & 63, w = tid >> 6;
  const int lrow = l & 15, k16 = l >> 4;
  const int m0 = blockIdx.x * 128 + w * 32;
  char* const h1t = lds + 98304 + w * 4096;  // per-wave 32x64 bf16 tile

  auto stage = [&](int buf, int nt) {
    char* w1p = lds + buf * 32768;
    char* w2s = lds + 65536 + buf * 16384;
    // W1 panel: 64 rows (n-cols of W1) x 32 chunks (K=256)
#pragma unroll
    for (int i = 0; i < 8; ++i) {
      int c = i * 256 + tid;
      int row = c >> 5, lch = c & 31;
      int gch = (lch & ~7) | ((lch & 7) ^ (row & 7));
      const unsigned short* gp = W1t + (size_t)(nt * 64 + row) * 256 + gch * 8;
      __builtin_amdgcn_global_load_lds(
          (const __attribute__((address_space(1))) void*)gp,
          (__attribute__((address_space(3))) void*)(w1p + (i * 256 + w * 64) * 16), 16, 0, 0);
    }
    // W2 slice: 128 rows (out cols c) x 8 chunks (64 k = this n-tile's H1 cols)
#pragma unroll
    for (int i = 0; i < 4; ++i) {
      int c = i * 256 + tid;
      int row = c >> 3, lch = c & 7;
      int gch = lch ^ (row & 7);
      const unsigned short* gp = W2t + (size_t)row * 832 + nt * 64 + gch * 8;
      __builtin_amdgcn_global_load_lds(
          (const __attribute__((address_space(1))) void*)gp,
          (__attribute__((address_space(3))) void*)(w2s + (i * 256 + w * 64) * 16), 16, 0, 0);
    }
  };

  // ---- A band: wave's 32 rows x 256 k in registers (rows >= M read garbage; rows
  // are independent through both GEMMs and stores are guarded, so it's inert) ----
  bf16x8 af[8][2];
#pragma unroll
  for (int t = 0; t < 8; ++t)
#pragma unroll
    for (int mi = 0; mi < 2; ++mi)
      af[t][mi] = *reinterpret_cast<const bf16x8*>(
          A + (size_t)(m0 + mi * 16 + lrow) * 256 + t * 32 + k16 * 8);

  stage(0, 0);
  __syncthreads();

  f32x4 acc2[2][8] = {};
  for (int nt = 0; nt < 13; ++nt) {
    const int cur = nt & 1;
    if (nt + 1 < 13) stage(cur ^ 1, nt + 1);  // issue-early prefetch
    const char* w1p = lds + cur * 32768;
    const char* w2s = lds + 65536 + cur * 16384;

    // ---- first gemm: acc1 = Aband @ W1panel^T ----
    f32x4 acc1[2][4] = {};
#pragma unroll
    for (int t = 0; t < 8; ++t) {
      bf16x8 bf[4];
#pragma unroll
      for (int ni = 0; ni < 4; ++ni) {
        int row = ni * 16 + lrow;
        int ch = t * 4 + k16;
        int sc = (ch & ~7) | ((ch & 7) ^ (row & 7));
        bf[ni] = *reinterpret_cast<const bf16x8*>(w1p + row * 512 + sc * 16);
      }
#pragma unroll
      for (int mi = 0; mi < 2; ++mi)
#pragma unroll
        for (int ni = 0; ni < 4; ++ni)
          acc1[mi][ni] = __builtin_amdgcn_mfma_f32_16x16x32_bf16(af[t][mi], bf[ni], acc1[mi][ni], 0, 0, 0);
    }

    // ---- epilogue-1: H1 tile (relu, bf16) -> per-wave LDS (XOR chunk swizzle) ----
#pragma unroll
    for (int mi = 0; mi < 2; ++mi) {
#pragma unroll
      for (int q = 0; q < 4; ++q) {
        int rl = mi * 16 + k16 * 4 + q;
        float rs = nd[m0 + rl];
#pragma unroll
        for (int ni = 0; ni < 4; ++ni) {
          int colc = ni * 16 + lrow;
          int jg = nt * 64 + colc;
          float bb = (jg < 800) ? b1[jg] : 0.f;  // pad cols hit zeroed W2t rows
          float v = fmaxf(acc1[mi][ni][q] * rs + bb, 0.f);
          int sc = (colc >> 3) ^ (rl & 7);
          *(unsigned short*)(h1t + rl * 128 + sc * 16 + (colc & 7) * 2) = f2bf(v);
        }
      }
    }

    // ---- second gemm: acc2 += H1tile @ W2slice^T (same-wave LDS, no barrier) ----
#pragma unroll
    for (int ks = 0; ks < 2; ++ks) {
      bf16x8 a2[2];
#pragma unroll
      for (int mi = 0; mi < 2; ++mi) {
        int rl = mi * 16 + lrow;
        int sc = (ks * 4 + k16) ^ (rl & 7);
        a2[mi] = *reinterpret_cast<const bf16x8*>(h1t + rl * 128 + sc * 16);
      }
#pragma unroll
      for (int ni = 0; ni < 8; ++ni) {
        int rc = ni * 16 + lrow;
        int sc = (ks * 4 + k16) ^ (rc & 7);
        bf16x8 b2v = *reinterpret_cast<const bf16x8*>(w2s + rc * 128 + sc * 16);
#pragma unroll
        for (int mi = 0; mi < 2; ++mi)
          acc2[mi][ni] = __builtin_amdgcn_mfma_f32_16x16x32_bf16(a2[mi], b2v, acc2[mi][ni], 0, 0, 0);
      }
    }
    __syncthreads();  // all waves done with buf[cur]; drains prefetch into buf[cur^1]
  }

  // ---- epilogue-2: T2b = bf16(acc2 * ns[r]) ----
#pragma unroll
  for (int mi = 0; mi < 2; ++mi) {
#pragma unroll
    for (int q = 0; q < 4; ++q) {
      int r = m0 + mi * 16 + k16 * 4 + q;
      if (r >= M) continue;
      float sn = ns[r];
#pragma unroll
      for (int ni = 0; ni < 8; ++ni) {
        int c = ni * 16 + lrow;
        T2b[(size_t)r * 128 + c] = f2bf(acc2[mi][ni][q] * sn);
      }
    }
  }
}

// ================= gemm8s: small-K GEMM (K = KT*32, KT<=8) — r10-proven ===========
template <int KT, int RELU>
__global__ __launch_bounds__(256) void gemm8s_kernel(
    const unsigned short* __restrict__ A, const unsigned short* __restrict__ Bt,
    unsigned short* __restrict__ C, int M, int Nreal, int NTn,
    const float* __restrict__ rowscale, const float* __restrict__ bias) {
  constexpr int K = KT * 32;
  constexpr int CPR = KT * 4;
  constexpr int ROWB = CPR * 16;
  constexpr int TC = 64 * CPR;
  __shared__ __align__(16) char lds[64 * ROWB];

  const int sw = xcd_swizzle(blockIdx.x, gridDim.x);
  const int mg = sw / NTn, nt = sw - mg * NTn;
  const int tid = threadIdx.x;
  const int l = tid & 63, w = tid >> 6;
  const int lrow = l & 15, k16 = l >> 4;
  const int m0 = mg * 128 + w * 32, n0 = nt * 64;

#pragma unroll
  for (int i = 0; i < TC / 256; ++i) {
    int c = i * 256 + tid;
    int row = c / CPR, lch = c % CPR;
    int gch = (lch & ~7) | ((lch & 7) ^ (row & 7));
    const unsigned short* gp = Bt + (size_t)(n0 + row) * K + gch * 8;
    __builtin_amdgcn_global_load_lds(
        (const __attribute__((address_space(1))) void*)gp,
        (__attribute__((address_space(3))) void*)(lds + (i * 256 + w * 64) * 16), 16, 0, 0);
  }

  bf16x8 af[KT][2];
#pragma unroll
  for (int t = 0; t < KT; ++t)
#pragma unroll
    for (int mi = 0; mi < 2; ++mi)
      af[t][mi] = *reinterpret_cast<const bf16x8*>(
          A + (size_t)(m0 + mi * 16 + lrow) * K + t * 32 + k16 * 8);

  __syncthreads();

  f32x4 acc[2][4] = {};
#pragma unroll
  for (int t = 0; t < KT; ++t) {
    bf16x8 bf[4];
#pragma unroll
    for (int ni = 0; ni < 4; ++ni) {
      int row = ni * 16 + lrow;
      int ch = t * 4 + k16;
      int sc = (ch & ~7) | ((ch & 7) ^ (row & 7));
      bf[ni] = *reinterpret_cast<const bf16x8*>(lds + row * ROWB + sc * 16);
    }
#pragma unroll
    for (int mi = 0; mi < 2; ++mi)
#pragma unroll
      for (int ni = 0; ni < 4; ++ni)
        acc[mi][ni] = __builtin_amdgcn_mfma_f32_16x16x32_bf16(af[t][mi], bf[ni], acc[mi][ni], 0, 0, 0);
  }

#pragma unroll
  for (int mi = 0; mi < 2; ++mi) {
#pragma unroll
    for (int q = 0; q < 4; ++q) {
      int r = m0 + mi * 16 + k16 * 4 + q;
      if (r >= M) continue;
      float rs = rowscale[r];
#pragma unroll
      for (int ni = 0; ni < 4; ++ni) {
        int c = n0 + ni * 16 + lrow;
        if (c >= Nreal) continue;
        float v = acc[mi][ni][q] * rs + bias[c];
        if (RELU) v = fmaxf(v, 0.f);
        C[(size_t)r * Nreal + c] = f2bf(v);
      }
    }
  }
}

// ================= gemm8l: K=800 GEMM, B-tile staged in 2 LDS phases — r10-proven ==
template <int OUT_BF>
__global__ __launch_bounds__(256) void gemm8l_kernel(
    const unsigned short* __restrict__ A, const unsigned short* __restrict__ Bt,
    void* __restrict__ C, int M, int N, int NTn,
    const float* __restrict__ rowscale) {
  constexpr int K = 800, KPAD = 832;
  constexpr int CPR = 52;
  constexpr int ROWB = CPR * 16;
  __shared__ __align__(16) char lds[64 * ROWB];

  const int sw = xcd_swizzle(blockIdx.x, gridDim.x);
  const int mg = sw / NTn, nt = sw - mg * NTn;
  const int tid = threadIdx.x;
  const int l = tid & 63, w = tid >> 6;
  const int lrow = l & 15, k16 = l >> 4;
  const int m0 = mg * 128 + w * 32, n0 = nt * 64;

  auto stage = [&](int phase) {
#pragma unroll
    for (int i = 0; i < 13; ++i) {
      int c = i * 256 + tid;
      int row = c / CPR, lch = c % CPR;
      int gch = phase * CPR + ((lch & ~3) | ((lch & 3) ^ (row & 3)));
      const unsigned short* gp = Bt + (size_t)(n0 + row) * KPAD + gch * 8;
      __builtin_amdgcn_global_load_lds(
          (const __attribute__((address_space(1))) void*)gp,
          (__attribute__((address_space(3))) void*)(lds + (i * 256 + w * 64) * 16), 16, 0, 0);
    }
  };

  f32x4 acc[2][4] = {};

  auto compute = [&](int t0, int t1, int phase) {
#pragma unroll 13
    for (int t = t0; t < t1; ++t) {
      bf16x8 a[2];
#pragma unroll
      for (int mi = 0; mi < 2; ++mi)
        a[mi] = *reinterpret_cast<const bf16x8*>(
            A + (size_t)(m0 + mi * 16 + lrow) * K + t * 32 + k16 * 8);
      bf16x8 bf[4];
#pragma unroll
      for (int ni = 0; ni < 4; ++ni) {
        int row = ni * 16 + lrow;
        int ch = t * 4 + k16 - phase * CPR;
        int sc = (ch & ~3) | ((ch & 3) ^ (row & 3));
        bf[ni] = *reinterpret_cast<const bf16x8*>(lds + row * ROWB + sc * 16);
      }
#pragma unroll
      for (int mi = 0; mi < 2; ++mi)
#pragma unroll
        for (int ni = 0; ni < 4; ++ni)
          acc[mi][ni] = __builtin_amdgcn_mfma_f32_16x16x32_bf16(a[mi], bf[ni], acc[mi][ni], 0, 0, 0);
    }
  };

  stage(0);
  __syncthreads();
  compute(0, 13, 0);
  __syncthreads();
  stage(1);
  __syncthreads();
  compute(13, 25, 1);

#pragma unroll
  for (int mi = 0; mi < 2; ++mi) {
#pragma unroll
    for (int q = 0; q < 4; ++q) {
      int r = m0 + mi * 16 + k16 * 4 + q;
      if (r >= M) continue;
      float rs = rowscale[r];
#pragma unroll
      for (int ni = 0; ni < 4; ++ni) {
        int c = n0 + ni * 16 + lrow;
        float v = acc[mi][ni][q] * rs;
        if (OUT_BF) ((unsigned short*)C)[(size_t)r * N + c] = f2bf(v);
        else ((float*)C)[(size_t)r * N + c] = v;
      }
    }
  }
}

extern "C" void kernel_launch(void* const* d_in, const int* in_sizes, int n_in,
                              void* d_out, int out_size, void* d_ws, size_t ws_size,
                              hipStream_t stream) {
  const float* x  = (const float*)d_in[0];
  const int* src  = (const int*)d_in[1];
  const int* dst  = (const int*)d_in[2];
  const float* W1 = (const float*)d_in[3];
  const float* b1 = (const float*)d_in[4];
  const float* W2 = (const float*)d_in[5];
  const float* b2 = (const float*)d_in[6];
  const float* W3 = (const float*)d_in[7];
  const float* b3 = (const float*)d_in[8];
  const float* W4 = (const float*)d_in[9];
  const float* b4 = (const float*)d_in[10];

  float* out_enc = (float*)d_out;                  // [NN,128]
  float* out_dec = out_enc + (size_t)NN * 128;     // [NN,256]

  // ---- workspace layout (~82 MB) ----
  float* ns = (float*)d_ws;                        // [NN]
  float* nd = ns + NN;                             // [NN]
  unsigned short* xb  = (unsigned short*)(nd + NN);  // [NN*256]
  unsigned short* T2b = xb + (size_t)NN * 256;     // [NN*128] bf16
  unsigned short* h2  = T2b + (size_t)NN * 128;    // [NN*128] bf16
  unsigned short* A1  = h2 + (size_t)NN * 128;     // [MROWS*256]
  unsigned short* A3  = A1 + (size_t)MROWS * 256;  // [MROWS*128]
  unsigned short* G4  = A3 + (size_t)MROWS * 128;  // [NN*256]
  unsigned short* H1  = G4 + (size_t)NN * 256;     // [MH*800]
  unsigned short* W1t = H1 + (size_t)MH * 800;     // [832*256]
  unsigned short* W2t = W1t + 832 * 256;           // [128*832]
  unsigned short* W3t = W2t + 128 * 832;           // [832*128]
  unsigned short* W4t = W3t + 832 * 128;           // [256*832]
  int* degs   = (int*)(W4t + 256 * 832);           // [NN]
  int* degd   = degs + NN;                         // [NN]
  int* cursor = degd + NN;                         // [NN]
  int* rowptr = cursor + NN;                       // [NN+1]
  int* col    = rowptr + NN + 1;                   // [NE]
  int* pscan  = col + NE;                          // [NN]
  int* bsum   = pscan + NN;                        // [SB]

  // ---- CSR build + norms (parallel scan; offset scan fused into rowptr_fix) ----
  zero_kernel<<<(3 * NN / 4 + 255) / 256, 256, 0, stream>>>((int4*)degs, 3 * NN / 4);
  deg_count_kernel<<<(NE + 255) / 256, 256, 0, stream>>>(src, dst, degs, degd, NE);
  pscan_norm_kernel<<<SB, 256, 0, stream>>>(degs, degd, pscan, bsum, ns, nd, NN);
  rowptr_fix_kernel<<<SB, 256, 0, stream>>>(pscan, bsum, rowptr, NN);
  csr_fill_kernel<<<(NE + 255) / 256, 256, 0, stream>>>(src, dst, rowptr, cursor, col, NE);

  // ---- weight conversion: one fused launch ----
  wt_convert_all_kernel<<<dim3(4, 2048), 256, 0, stream>>>(
      W1, W2, W3, W4, W1t, W2t, W3t, W4t);

  // grids
  const int GS = 157 * 13;   // gemm8s L3 (Npad 832)
  const int GL4 = 157 * 4;   // gemm8l L4 (N=256)

  // ---- L1+L2 fused: xb -> gather -> A1; gemm9f -> T2b (no H1 round-trip) ----
  scale_cvt_kernel<<<(NN * 32 + 255) / 256, 256, 0, stream>>>(x, ns, xb);
  gatherb_kernel<256, 0><<<(NN + 7) / 8, 256, 0, stream>>>(
      xb, rowptr, col, nullptr, nullptr, nullptr, A1, nullptr, NN);
  gemm9f_kernel<<<157, 256, 0, stream>>>(A1, W1t, W2t, T2b, NN, nd, ns, b1);

  // ---- L2 gather: -> h2s=bf16(h2*ns) + sigmoid(out_enc) ----
  gatherb_kernel<128, 1><<<(NN + 15) / 16, 256, 0, stream>>>(
      T2b, rowptr, col, nd, b2, ns, h2, out_enc, NN);

  // ---- L3: gather(h2s) -> A3; gemm8s (K=128 -> 800) relu -> H1 ----
  gatherb_kernel<128, 0><<<(NN + 15) / 16, 256, 0, stream>>>(
      h2, rowptr, col, nullptr, nullptr, nullptr, A3, nullptr, NN);
  gemm8s_kernel<4, 1><<<GS, 256, 0, stream>>>(A3, W3t, H1, NN, 800, 13, nd, b3);

  // ---- L4: gemm8l (800 -> 256)*ns -> bf16 G4; gather -> sigmoid(out_dec) ----
  gemm8l_kernel<1><<<GL4, 256, 0, stream>>>(H1, W4t, G4, NN, 256, 4, ns);
  gatherb_kernel<256, 2><<<(NN + 7) / 8, 256, 0, stream>>>(
      G4, rowptr, col, nd, b4, nullptr, nullptr, out_dec, NN);
}

// Round 16
// 245.032 us; speedup vs baseline: 1.2464x; 1.0091x over previous
//
#include <hip/hip_runtime.h>
#include <math.h>

constexpr int NN = 20000;   // nodes
constexpr int NE = 320000;  // edges
constexpr int MROWS = 20224; // A1/A3 row padding
constexpr int SB = 79;      // scan blocks (79*256 >= NN)

typedef __bf16 bf16x8 __attribute__((ext_vector_type(8)));
typedef float f32x4 __attribute__((ext_vector_type(4)));

__device__ __forceinline__ unsigned short f2bf(float f) {
  unsigned int u = __float_as_uint(f);
  unsigned int r = (u + 0x7FFFu + ((u >> 16) & 1u)) >> 16;
  return (unsigned short)r;
}

// ---------------- fast zero ----------------
__global__ __launch_bounds__(256) void zero_kernel(int4* __restrict__ p, int n4) {
  int i = blockIdx.x * 256 + threadIdx.x;
  if (i < n4) p[i] = make_int4(0, 0, 0, 0);
}

// ---------------- degree count ----------------
__global__ void deg_count_kernel(const int* __restrict__ src, const int* __restrict__ dst,
                                 int* __restrict__ degs, int* __restrict__ degd, int nE) {
  int e = blockIdx.x * blockDim.x + threadIdx.x;
  if (e < nE) {
    atomicAdd(degs + src[e], 1);
    atomicAdd(degd + dst[e], 1);
  }
}

// ---------------- scan phase B: norms + block-local exclusive scan + block sums ----
__global__ __launch_bounds__(256) void pscan_norm_kernel(
    const int* __restrict__ degs, const int* __restrict__ degd,
    int* __restrict__ pscan, int* __restrict__ bsum,
    float* __restrict__ ns, float* __restrict__ nd, int n) {
  __shared__ int s[256];
  int t = threadIdx.x;
  int idx = blockIdx.x * 256 + t;
  int val = 0;
  if (idx < n) {
    int dd = degd[idx];
    val = dd;
    ns[idx] = rsqrtf(fmaxf((float)degs[idx], 1.0f));
    nd[idx] = rsqrtf(fmaxf((float)dd, 1.0f));
  }
  s[t] = val;
  __syncthreads();
#pragma unroll
  for (int off = 1; off < 256; off <<= 1) {
    int v = (t >= off) ? s[t - off] : 0;
    __syncthreads();
    s[t] += v;
    __syncthreads();
  }
  if (idx < n) pscan[idx] = s[t] - val;  // exclusive within block
  if (t == 255) bsum[blockIdx.x] = s[255];
}

// ---------------- scan phase C+D fused: rowptr = pscan + offset(block) -------------
__global__ __launch_bounds__(256) void rowptr_fix_kernel(
    const int* __restrict__ pscan, const int* __restrict__ bsum,
    int* __restrict__ rowptr, int n) {
  __shared__ int s[128];
  int t = threadIdx.x;
  if (t < 128) s[t] = (t < SB) ? bsum[t] : 0;
  __syncthreads();
#pragma unroll
  for (int off = 1; off < 128; off <<= 1) {
    int v = (t < 128 && t >= off) ? s[t - off] : 0;
    __syncthreads();
    if (t < 128) s[t] += v;
    __syncthreads();
  }
  int idx = blockIdx.x * 256 + t;
  int boff = (blockIdx.x == 0) ? 0 : s[blockIdx.x - 1];
  if (idx < n) rowptr[idx] = pscan[idx] + boff;
  if (idx == 0) rowptr[n] = NE;
}

// ---------------- CSR fill ----------------
__global__ void csr_fill_kernel(const int* __restrict__ src, const int* __restrict__ dst,
                                const int* __restrict__ rowptr, int* __restrict__ cursor,
                                int* __restrict__ col, int nE) {
  int e = blockIdx.x * blockDim.x + threadIdx.x;
  if (e < nE) {
    int d = dst[e];
    int p = atomicAdd(cursor + d, 1);
    col[rowptr[d] + p] = src[e];
  }
}

// ---------------- fused weight convert: all 4 Wt[Npad][Kpad] in one launch ---------
__global__ __launch_bounds__(256) void wt_convert_all_kernel(
    const float* __restrict__ W1, const float* __restrict__ W2,
    const float* __restrict__ W3, const float* __restrict__ W4,
    unsigned short* __restrict__ W1t, unsigned short* __restrict__ W2t,
    unsigned short* __restrict__ W3t, unsigned short* __restrict__ W4t) {
  int n = blockIdx.y;
  int k = blockIdx.x * 256 + threadIdx.x;
  const float* W; unsigned short* Wt; int K, N, Kpad;
  if (n < 832)       { W = W1; Wt = W1t; K = 256; N = 800; Kpad = 256; }
  else if (n < 960)  { n -= 832;  W = W2; Wt = W2t; K = 800; N = 128; Kpad = 832; }
  else if (n < 1792) { n -= 960;  W = W3; Wt = W3t; K = 128; N = 800; Kpad = 128; }
  else               { n -= 1792; W = W4; Wt = W4t; K = 800; N = 256; Kpad = 832; }
  if (k >= Kpad) return;
  float v = (n < N && k < K) ? W[(size_t)k * N + n] : 0.f;
  Wt[(size_t)n * Kpad + k] = f2bf(v);
}

// ---------------- xb = bf16(x * ns[row]) pre-pass ----------------
__global__ __launch_bounds__(256) void scale_cvt_kernel(
    const float* __restrict__ x, const float* __restrict__ ns,
    unsigned short* __restrict__ xb) {
  int t = blockIdx.x * 256 + threadIdx.x;
  if (t >= NN * 32) return;
  int node = t >> 5;
  float sc = ns[node];
  float4 v1 = reinterpret_cast<const float4*>(x)[t * 2];
  float4 v2 = reinterpret_cast<const float4*>(x)[t * 2 + 1];
  uint4 o;
  o.x = f2bf(v1.x * sc) | ((unsigned)f2bf(v1.y * sc) << 16);
  o.y = f2bf(v1.z * sc) | ((unsigned)f2bf(v1.w * sc) << 16);
  o.z = f2bf(v2.x * sc) | ((unsigned)f2bf(v2.y * sc) << 16);
  o.w = f2bf(v2.z * sc) | ((unsigned)f2bf(v2.w * sc) << 16);
  reinterpret_cast<uint4*>(xb)[t] = o;
}

// ---------------- bf16 CSR gather (edge loop unrolled x2) ----------------
template <int F, int EPI>
__global__ __launch_bounds__(256) void gatherb_kernel(
    const unsigned short* __restrict__ in, const int* __restrict__ rowptr,
    const int* __restrict__ col, const float* __restrict__ sDst,
    const float* __restrict__ bias, const float* __restrict__ snext,
    unsigned short* __restrict__ out, float* __restrict__ out2, int n) {
  constexpr int LPN = F / 8;
  constexpr int NPB = 256 / LPN;
  const int tid = threadIdx.x;
  const int node = blockIdx.x * NPB + tid / LPN;
  const int j = tid % LPN;
  if (node >= n) return;
  const int e0 = rowptr[node], e1 = rowptr[node + 1];
  float a[8] = {0.f, 0.f, 0.f, 0.f, 0.f, 0.f, 0.f, 0.f};
  int e = e0;
  for (; e + 1 < e1; e += 2) {
    int c0 = col[e], c1 = col[e + 1];
    uint4 u0 = *reinterpret_cast<const uint4*>(in + (size_t)c0 * F + j * 8);
    uint4 u1 = *reinterpret_cast<const uint4*>(in + (size_t)c1 * F + j * 8);
    a[0] += __uint_as_float(u0.x << 16);
    a[1] += __uint_as_float(u0.x & 0xffff0000u);
    a[2] += __uint_as_float(u0.y << 16);
    a[3] += __uint_as_float(u0.y & 0xffff0000u);
    a[4] += __uint_as_float(u0.z << 16);
    a[5] += __uint_as_float(u0.z & 0xffff0000u);
    a[6] += __uint_as_float(u0.w << 16);
    a[7] += __uint_as_float(u0.w & 0xffff0000u);
    a[0] += __uint_as_float(u1.x << 16);
    a[1] += __uint_as_float(u1.x & 0xffff0000u);
    a[2] += __uint_as_float(u1.y << 16);
    a[3] += __uint_as_float(u1.y & 0xffff0000u);
    a[4] += __uint_as_float(u1.z << 16);
    a[5] += __uint_as_float(u1.z & 0xffff0000u);
    a[6] += __uint_as_float(u1.w << 16);
    a[7] += __uint_as_float(u1.w & 0xffff0000u);
  }
  if (e < e1) {
    int c = col[e];
    uint4 u = *reinterpret_cast<const uint4*>(in + (size_t)c * F + j * 8);
    a[0] += __uint_as_float(u.x << 16);
    a[1] += __uint_as_float(u.x & 0xffff0000u);
    a[2] += __uint_as_float(u.y << 16);
    a[3] += __uint_as_float(u.y & 0xffff0000u);
    a[4] += __uint_as_float(u.z << 16);
    a[5] += __uint_as_float(u.z & 0xffff0000u);
    a[6] += __uint_as_float(u.w << 16);
    a[7] += __uint_as_float(u.w & 0xffff0000u);
  }
  if (EPI == 0) {
    uint4 o;
    o.x = f2bf(a[0]) | ((unsigned)f2bf(a[1]) << 16);
    o.y = f2bf(a[2]) | ((unsigned)f2bf(a[3]) << 16);
    o.z = f2bf(a[4]) | ((unsigned)f2bf(a[5]) << 16);
    o.w = f2bf(a[6]) | ((unsigned)f2bf(a[7]) << 16);
    *reinterpret_cast<uint4*>(out + (size_t)node * F + j * 8) = o;
    return;
  }
  const float sd = sDst[node];
  float v[8];
#pragma unroll
  for (int k = 0; k < 8; ++k) v[k] = a[k] * sd + bias[j * 8 + k];
  if (EPI == 1) {
    float sn = snext[node];
    uint4 o;
    o.x = f2bf(v[0] * sn) | ((unsigned)f2bf(v[1] * sn) << 16);
    o.y = f2bf(v[2] * sn) | ((unsigned)f2bf(v[3] * sn) << 16);
    o.z = f2bf(v[4] * sn) | ((unsigned)f2bf(v[5] * sn) << 16);
    o.w = f2bf(v[6] * sn) | ((unsigned)f2bf(v[7] * sn) << 16);
    *reinterpret_cast<uint4*>(out + (size_t)node * F + j * 8) = o;
  }
  float4 s1, s2;
  s1.x = 1.0f / (1.0f + expf(-v[0]));
  s1.y = 1.0f / (1.0f + expf(-v[1]));
  s1.z = 1.0f / (1.0f + expf(-v[2]));
  s1.w = 1.0f / (1.0f + expf(-v[3]));
  s2.x = 1.0f / (1.0f + expf(-v[4]));
  s2.y = 1.0f / (1.0f + expf(-v[5]));
  s2.z = 1.0f / (1.0f + expf(-v[6]));
  s2.w = 1.0f / (1.0f + expf(-v[7]));
  *reinterpret_cast<float4*>(out2 + (size_t)node * F + j * 8) = s1;
  *reinterpret_cast<float4*>(out2 + (size_t)node * F + j * 8 + 4) = s2;
}

// ================= gemm9v2: fused back-to-back GEMM (layer pair) ==================
// Out[r][c] = ns[r] * SUM_j relu(nd[r]*(A[r,:] . Wa[j,:]) + ba[j]) * Wb[c][j]
// Grid 314 x 64 rows; 4 waves x 16 rows. Per nt (13 x 64-col tiles of the hidden
// dim): stage Wa panel [64][K1] + Wb slice [N2][64] to LDS (single buffer, 58KB
// -> 2 blocks/CU, cross-block overlap hides stage drain); gemm1 -> per-wave
// H-tile in LDS (stride 144B, pad kills 128B aliasing; same-wave RAW via lgkmcnt);
// gemm2 accumulates acc2 over all nt. Pad cols (>=800) hit zeroed Wa rows / Wb
// cols -> contribute 0. Rows >= M flow garbage through row-independent math;
// final store guarded.
template <int KT1, int NOUT>
__global__ __launch_bounds__(256) void gemm9v2_kernel(
    const unsigned short* __restrict__ A,    // [MROWS][K1] bf16
    const unsigned short* __restrict__ Wa,   // [832][K1] bf16
    const unsigned short* __restrict__ Wb,   // [N2][832] bf16
    unsigned short* __restrict__ Out,        // [NN][N2] bf16
    int M, const float* __restrict__ nd, const float* __restrict__ ns,
    const float* __restrict__ ba) {
  constexpr int K1 = KT1 * 32;
  constexpr int N2 = NOUT * 16;
  constexpr int ROWB1 = K1 * 2;         // Wa panel row bytes
  constexpr int CPR1 = K1 / 8;          // Wa chunks per row
  constexpr int W1B = 64 * ROWB1;       // Wa panel bytes
  constexpr int W2B = N2 * 128;         // Wb slice bytes (row = 64 cols * 2B)
  constexpr int HST = 144;              // H-tile row stride (16B pad)
  __shared__ __align__(16) char lds[W1B + W2B + 4 * 16 * HST];

  const int tid = threadIdx.x;
  const int l = tid & 63, w = tid >> 6;
  const int lrow = l & 15, k16 = l >> 4;
  const int m0 = blockIdx.x * 64 + w * 16;
  char* const w1p = lds;
  char* const w2s = lds + W1B;
  char* const h1t = lds + W1B + W2B + w * 16 * HST;

  auto stage = [&](int nt) {
    // Wa panel: 64 rows x CPR1 chunks
#pragma unroll
    for (int i = 0; i < 64 * CPR1 / 256; ++i) {
      int c = i * 256 + tid;
      int row = c / CPR1, lch = c % CPR1;
      int gch = (lch & ~7) | ((lch & 7) ^ (row & 7));
      const unsigned short* gp = Wa + (size_t)(nt * 64 + row) * K1 + gch * 8;
      __builtin_amdgcn_global_load_lds(
          (const __attribute__((address_space(1))) void*)gp,
          (__attribute__((address_space(3))) void*)(w1p + (i * 256 + w * 64) * 16), 16, 0, 0);
    }
    // Wb slice: N2 rows x 8 chunks (64 hidden-cols)
#pragma unroll
    for (int i = 0; i < N2 * 8 / 256; ++i) {
      int c = i * 256 + tid;
      int row = c >> 3, lch = c & 7;
      int gch = lch ^ (row & 7);
      const unsigned short* gp = Wb + (size_t)row * 832 + nt * 64 + gch * 8;
      __builtin_amdgcn_global_load_lds(
          (const __attribute__((address_space(1))) void*)gp,
          (__attribute__((address_space(3))) void*)(w2s + (i * 256 + w * 64) * 16), 16, 0, 0);
    }
  };

  // ---- per-wave A band: 16 rows x K1 in registers ----
  bf16x8 af[KT1];
#pragma unroll
  for (int t = 0; t < KT1; ++t)
    af[t] = *reinterpret_cast<const bf16x8*>(
        A + (size_t)(m0 + lrow) * K1 + t * 32 + k16 * 8);

  stage(0);
  __syncthreads();

  f32x4 acc2[NOUT] = {};
  for (int nt = 0; nt < 13; ++nt) {
    // ---- gemm1: acc1 = Aband @ WaPanel^T ----
    f32x4 acc1[4] = {};
#pragma unroll
    for (int t = 0; t < KT1; ++t) {
      bf16x8 bf[4];
#pragma unroll
      for (int ni = 0; ni < 4; ++ni) {
        int row = ni * 16 + lrow;
        int ch = t * 4 + k16;
        int sc = (ch & ~7) | ((ch & 7) ^ (row & 7));
        bf[ni] = *reinterpret_cast<const bf16x8*>(w1p + row * ROWB1 + sc * 16);
      }
#pragma unroll
      for (int ni = 0; ni < 4; ++ni)
        acc1[ni] = __builtin_amdgcn_mfma_f32_16x16x32_bf16(af[t], bf[ni], acc1[ni], 0, 0, 0);
    }

    // ---- epilogue-1: relu(nd*acc1 + b) -> per-wave H tile (padded stride) ----
#pragma unroll
    for (int q = 0; q < 4; ++q) {
      int rl = k16 * 4 + q;
      float rs = nd[m0 + rl];
#pragma unroll
      for (int ni = 0; ni < 4; ++ni) {
        int colc = ni * 16 + lrow;
        int jg = nt * 64 + colc;
        float bb = (jg < 800) ? ba[jg] : 0.f;
        float v = fmaxf(acc1[ni][q] * rs + bb, 0.f);
        *(unsigned short*)(h1t + rl * HST + (colc >> 3) * 16 + (colc & 7) * 2) = f2bf(v);
      }
    }

    // ---- gemm2: acc2 += Htile @ WbSlice^T (same-wave LDS RAW via lgkmcnt) ----
#pragma unroll
    for (int ks = 0; ks < 2; ++ks) {
      bf16x8 a2 = *reinterpret_cast<const bf16x8*>(h1t + lrow * HST + (ks * 4 + k16) * 16);
#pragma unroll
      for (int ni = 0; ni < NOUT; ++ni) {
        int rc = ni * 16 + lrow;
        int sc = (ks * 4 + k16) ^ (rc & 7);
        bf16x8 b2v = *reinterpret_cast<const bf16x8*>(w2s + rc * 128 + sc * 16);
        acc2[ni] = __builtin_amdgcn_mfma_f32_16x16x32_bf16(a2, b2v, acc2[ni], 0, 0, 0);
      }
    }
    __syncthreads();                 // all waves done reading this nt's panels
    if (nt + 1 < 13) {
      stage(nt + 1);
      __syncthreads();               // staging drained (vmcnt(0) at barrier)
    }
  }

  // ---- epilogue-2: Out = bf16(acc2 * ns[r]) ----
#pragma unroll
  for (int q = 0; q < 4; ++q) {
    int r = m0 + k16 * 4 + q;
    if (r >= M) continue;
    float sn = ns[r];
#pragma unroll
    for (int ni = 0; ni < NOUT; ++ni) {
      int c = ni * 16 + lrow;
      Out[(size_t)r * N2 + c] = f2bf(acc2[ni][q] * sn);
    }
  }
}

extern "C" void kernel_launch(void* const* d_in, const int* in_sizes, int n_in,
                              void* d_out, int out_size, void* d_ws, size_t ws_size,
                              hipStream_t stream) {
  const float* x  = (const float*)d_in[0];
  const int* src  = (const int*)d_in[1];
  const int* dst  = (const int*)d_in[2];
  const float* W1 = (const float*)d_in[3];
  const float* b1 = (const float*)d_in[4];
  const float* W2 = (const float*)d_in[5];
  const float* b2 = (const float*)d_in[6];
  const float* W3 = (const float*)d_in[7];
  const float* b3 = (const float*)d_in[8];
  const float* W4 = (const float*)d_in[9];
  const float* b4 = (const float*)d_in[10];

  float* out_enc = (float*)d_out;                  // [NN,128]
  float* out_dec = out_enc + (size_t)NN * 128;     // [NN,256]

  // ---- workspace layout (~50 MB) ----
  float* ns = (float*)d_ws;                        // [NN]
  float* nd = ns + NN;                             // [NN]
  unsigned short* xb  = (unsigned short*)(nd + NN);  // [NN*256]
  unsigned short* T2b = xb + (size_t)NN * 256;     // [NN*128] bf16 (L1+L2 out)
  unsigned short* h2  = T2b + (size_t)NN * 128;    // [NN*128] bf16 (h2*ns)
  unsigned short* A1  = h2 + (size_t)NN * 128;     // [MROWS*256]
  unsigned short* A3  = A1 + (size_t)MROWS * 256;  // [MROWS*128]
  unsigned short* G4  = A3 + (size_t)MROWS * 128;  // [NN*256] bf16 (L3+L4 out)
  unsigned short* W1t = G4 + (size_t)NN * 256;     // [832*256]
  unsigned short* W2t = W1t + 832 * 256;           // [128*832]
  unsigned short* W3t = W2t + 128 * 832;           // [832*128]
  unsigned short* W4t = W3t + 832 * 128;           // [256*832]
  int* degs   = (int*)(W4t + 256 * 832);           // [NN]
  int* degd   = degs + NN;                         // [NN]
  int* cursor = degd + NN;                         // [NN]
  int* rowptr = cursor + NN;                       // [NN+1]
  int* col    = rowptr + NN + 1;                   // [NE]
  int* pscan  = col + NE;                          // [NN]
  int* bsum   = pscan + NN;                        // [SB]

  // ---- CSR build + norms (parallel scan) ----
  zero_kernel<<<(3 * NN / 4 + 255) / 256, 256, 0, stream>>>((int4*)degs, 3 * NN / 4);
  deg_count_kernel<<<(NE + 255) / 256, 256, 0, stream>>>(src, dst, degs, degd, NE);
  pscan_norm_kernel<<<SB, 256, 0, stream>>>(degs, degd, pscan, bsum, ns, nd, NN);
  rowptr_fix_kernel<<<SB, 256, 0, stream>>>(pscan, bsum, rowptr, NN);
  csr_fill_kernel<<<(NE + 255) / 256, 256, 0, stream>>>(src, dst, rowptr, cursor, col, NE);

  // ---- weight conversion: one fused launch ----
  wt_convert_all_kernel<<<dim3(4, 2048), 256, 0, stream>>>(
      W1, W2, W3, W4, W1t, W2t, W3t, W4t);

  // ---- L1+L2 fused: xb -> gather -> A1; gemm9v2<8,8> -> T2b ----
  scale_cvt_kernel<<<(NN * 32 + 255) / 256, 256, 0, stream>>>(x, ns, xb);
  gatherb_kernel<256, 0><<<(NN + 7) / 8, 256, 0, stream>>>(
      xb, rowptr, col, nullptr, nullptr, nullptr, A1, nullptr, NN);
  gemm9v2_kernel<8, 8><<<314, 256, 0, stream>>>(A1, W1t, W2t, T2b, NN, nd, ns, b1);

  // ---- L2 gather: -> h2s=bf16(h2*ns) + sigmoid(out_enc) ----
  gatherb_kernel<128, 1><<<(NN + 15) / 16, 256, 0, stream>>>(
      T2b, rowptr, col, nd, b2, ns, h2, out_enc, NN);

  // ---- L3+L4 fused: gather(h2s) -> A3; gemm9v2<4,16> -> G4 ----
  gatherb_kernel<128, 0><<<(NN + 15) / 16, 256, 0, stream>>>(
      h2, rowptr, col, nullptr, nullptr, nullptr, A3, nullptr, NN);
  gemm9v2_kernel<4, 16><<<314, 256, 0, stream>>>(A3, W3t, W4t, G4, NN, nd, ns, b3);

  // ---- L4 gather: -> sigmoid(out_dec) ----
  gatherb_kernel<256, 2><<<(NN + 7) / 8, 256, 0, stream>>>(
      G4, rowptr, col, nd, b4, nullptr, nullptr, out_dec, NN);
}